// Round 1
// baseline (395.696 us; speedup 1.0000x reference)
//
#include <hip/hip_runtime.h>

#define NN 20000
#define NE 320000
#define FIN 64
#define HD 256
#define NC 10
#define NG 64
#define NB ((NN + 255) / 256)      // 79 scan blocks
#define EBMAX (NE + 15 * NN + 16)  // padded CSR upper bound (u16 slots)

typedef unsigned short u16;
typedef unsigned int u32;
typedef __attribute__((ext_vector_type(8))) short short8;   // 8 bf16 (4 VGPRs)
typedef __attribute__((ext_vector_type(4))) float f32x4;    // 4 fp32 acc

__device__ __forceinline__ float bf2f(u16 u) {
    union { u32 i; float f; } v; v.i = ((u32)u) << 16; return v.f;
}
__device__ __forceinline__ u16 f2bf(float f) {
    union { float f; u32 i; } v; v.f = f;
    u32 r = v.i + 0x7fffu + ((v.i >> 16) & 1u);   // RNE
    return (u16)(r >> 16);
}

// ---------------- degree count + graph bounds (degi zeroed by memset) ------
__global__ void k_deg(const int* __restrict__ col, int* __restrict__ degi,
                      const int* __restrict__ batch, int* __restrict__ gstart) {
    int i = blockIdx.x * 256 + threadIdx.x;
    if (i < NE) atomicAdd(&degi[col[i]], 1);
    if (i < NN) {
        int b = batch[i];
        int prev = (i == 0) ? -1 : batch[i - 1];
        if (b != prev) gstart[b] = i;
    }
}

// ---------------- pad-fill ebuf with sentinel NN (0x4E20) ------------------
__global__ void k_pad(u32* __restrict__ ebuf32) {
    int i = blockIdx.x * 256 + threadIdx.x;
    if (i < EBMAX / 2) ebuf32[i] = 0x4E204E20u;   // two u16 = NN, NN
}

// ---------------- scan stage 1: padded-degree block scan + block sums ------
__global__ __launch_bounds__(256) void k_scan1(const int* __restrict__ degi,
                                               int* __restrict__ rowptr,
                                               int* __restrict__ bsum) {
    int t = threadIdx.x;
    int i = blockIdx.x * 256 + t;
    int v = (i < NN) ? ((degi[i] + 15) & ~15) : 0;   // padded degree
    int lane = t & 63, wid = t >> 6;
    int x = v;
#pragma unroll
    for (int off = 1; off < 64; off <<= 1) {
        int y = __shfl_up(x, off);
        if (lane >= off) x += y;
    }
    __shared__ int ws[4];
    if (lane == 63) ws[wid] = x;
    __syncthreads();
    int woff = 0;
    for (int w = 0; w < wid; ++w) woff += ws[w];
    if (i < NN) rowptr[i] = woff + x - v;
    if (t == 255) bsum[blockIdx.x] = woff + x;
}

// ---------------- scan 2+3 fused: fixup + cursor + dinv + u0 (+zero row NN)
__global__ void k_scan3(const int* __restrict__ degi, const int* __restrict__ bsum,
                        int* __restrict__ rowptr, int* __restrict__ cursor,
                        float* __restrict__ dinv,
                        const float* __restrict__ x, u16* __restrict__ u0) {
    __shared__ int pref[NB];
    if (threadIdx.x < NB) pref[threadIdx.x] = bsum[threadIdx.x];
    __syncthreads();
    if (threadIdx.x == 0) {
        int run = 0;
        for (int k = 0; k < NB; ++k) { int t = pref[k]; pref[k] = run; run += t; }
    }
    __syncthreads();
    int i = blockIdx.x * 256 + threadIdx.x;
    if (i < NN) {
        int dg = degi[i];
        int rp = rowptr[i] + pref[i >> 8];
        rowptr[i] = rp;
        cursor[i] = rp;
        dinv[i] = rsqrtf((float)(1 + dg));
        if (i == NN - 1) rowptr[NN] = rp + ((dg + 15) & ~15);
    }
    if (i < NN * FIN / 4) {
        int node = i >> 4;
        float d = rsqrtf((float)(1 + degi[node]));
        float4 v = *(const float4*)&x[(size_t)i * 4];
        u32 lo = (u32)f2bf(v.x * d) | ((u32)f2bf(v.y * d) << 16);
        u32 hi = (u32)f2bf(v.z * d) | ((u32)f2bf(v.w * d) << 16);
        *(uint2*)&u0[(size_t)i * 4] = make_uint2(lo, hi);
    }
    if (blockIdx.x == 0 && threadIdx.x < FIN) u0[(size_t)NN * FIN + threadIdx.x] = 0;  // dummy row
}

// ---------------- fill CSR buckets (u16 payload) ----------------
__global__ void k_fill(const int* __restrict__ row, const int* __restrict__ col,
                       int* __restrict__ cursor, u16* __restrict__ ebuf) {
    int e = blockIdx.x * 256 + threadIdx.x;
    if (e < NE) {
        int c = col[e];
        int pos = atomicAdd(&cursor[c], 1);
        ebuf[pos] = (u16)row[e];
    }
}

// ---------------- LDS-tiled transpose+cast of all 5 W ----------------
__global__ __launch_bounds__(256) void k_trans(const float* __restrict__ W0, const float* __restrict__ W1,
                                               const float* __restrict__ W2, const float* __restrict__ W3,
                                               const float* __restrict__ W4,
                                               u16* __restrict__ T0, u16* __restrict__ T1,
                                               u16* __restrict__ T2, u16* __restrict__ T3,
                                               u16* __restrict__ T4) {
    int l = blockIdx.z;
    const float* W = (l == 0) ? W0 : (l == 1) ? W1 : (l == 2) ? W2 : (l == 3) ? W3 : W4;
    u16* T = (l == 0) ? T0 : (l == 1) ? T1 : (l == 2) ? T2 : (l == 3) ? T3 : T4;
    int K = (l == 0) ? FIN : HD;
    int k0 = blockIdx.x * 32;
    if (k0 >= K) return;
    int n0 = blockIdx.y * 32;
    __shared__ float tile[32][33];
    int tx = threadIdx.x & 31, ty = threadIdx.x >> 5;
#pragma unroll
    for (int r = 0; r < 32; r += 8)
        tile[ty + r][tx] = W[(size_t)(k0 + ty + r) * HD + n0 + tx];
    __syncthreads();
#pragma unroll
    for (int r = 0; r < 32; r += 8)
        T[(size_t)(n0 + ty + r) * K + k0 + tx] = f2bf(tile[tx][ty + r]);
}

// ============ FUSED gather(aggregate) + MFMA matmul, one 32-row tile/block ==
// Phase 1: gather the 32 rows' normalized aggregation into LDS Asm (bf16,
//          identical fp32-accum -> bf16 rounding as the old B2 path).
// Phase 2: Asm x Wt MFMA loop (Bsm staged per 32-k chunk), relu+bias(+dinv)
//          epilogue straight to O. Removes the B2 global round trip and one
//          dispatch boundary per layer. U != O (ping-pong) so no hazard.
__global__ __launch_bounds__(256, 3) void k_fused(const u16* __restrict__ U,
                                                  const int* __restrict__ rowptr,
                                                  const u16* __restrict__ ebuf,
                                                  const float* __restrict__ dinv,
                                                  const u16* __restrict__ Wt,
                                                  const float* __restrict__ bias,
                                                  u16* __restrict__ O,
                                                  int K, int scaleOut) {
    __shared__ u16 Asm[32][264];     // 32 rows x (K<=256 + 8 pad) bf16
    __shared__ u16 Bsm[256][40];
    __shared__ float bs[HD];
    const int m0 = blockIdx.x * 32;  // 625 * 32 == 20000, no partial tiles
    const int t = threadIdx.x;
    const int wave = t >> 6;
    const int lane = t & 63;
    bs[t] = bias[t];
    if (blockIdx.x == 0) O[(size_t)NN * HD + t] = 0;   // keep dummy row zero

    // ---------------- gather phase ----------------
    if (K == HD) {
        // 256-wide rows: task = node-half (128 feats), 64 tasks, 16/wave
        const int grp = lane >> 4;       // 0..3
        const int seg = lane & 15;       // 16-B segment within half
        for (int task = wave; task < 64; task += 4) {
            const int row = task >> 1;
            const int n = m0 + row;
            const int fbase = (task & 1) * 128 + seg * 8;
            const int s = rowptr[n], e = rowptr[n + 1];
            float acc[8];
            if (grp == 0) {              // self-loop
                uint4 v = *(const uint4*)&U[(size_t)n * HD + fbase];
                acc[0] = bf2f((u16)(v.x & 0xffff)); acc[1] = bf2f((u16)(v.x >> 16));
                acc[2] = bf2f((u16)(v.y & 0xffff)); acc[3] = bf2f((u16)(v.y >> 16));
                acc[4] = bf2f((u16)(v.z & 0xffff)); acc[5] = bf2f((u16)(v.z >> 16));
                acc[6] = bf2f((u16)(v.w & 0xffff)); acc[7] = bf2f((u16)(v.w >> 16));
            } else {
#pragma unroll
                for (int k = 0; k < 8; ++k) acc[k] = 0.f;
            }
            for (int j = s; j < e; j += 16) {
                int myid = (lane < 16) ? (int)ebuf[j + lane] : 0;  // pads -> row NN
                uint4 v[4];
#pragma unroll
                for (int k = 0; k < 4; ++k) {
                    int r = __shfl(myid, grp * 4 + k);
                    v[k] = *(const uint4*)&U[(size_t)r * HD + fbase];
                }
#pragma unroll
                for (int k = 0; k < 4; ++k) {
                    acc[0] += bf2f((u16)(v[k].x & 0xffff)); acc[1] += bf2f((u16)(v[k].x >> 16));
                    acc[2] += bf2f((u16)(v[k].y & 0xffff)); acc[3] += bf2f((u16)(v[k].y >> 16));
                    acc[4] += bf2f((u16)(v[k].z & 0xffff)); acc[5] += bf2f((u16)(v[k].z >> 16));
                    acc[6] += bf2f((u16)(v[k].w & 0xffff)); acc[7] += bf2f((u16)(v[k].w >> 16));
                }
            }
#pragma unroll
            for (int k = 0; k < 8; ++k) {
                acc[k] += __shfl_xor(acc[k], 16);
                acc[k] += __shfl_xor(acc[k], 32);
            }
            if (grp == 0) {
                float d = dinv[n];
                uint4 o;
                o.x = (u32)f2bf(acc[0] * d) | ((u32)f2bf(acc[1] * d) << 16);
                o.y = (u32)f2bf(acc[2] * d) | ((u32)f2bf(acc[3] * d) << 16);
                o.z = (u32)f2bf(acc[4] * d) | ((u32)f2bf(acc[5] * d) << 16);
                o.w = (u32)f2bf(acc[6] * d) | ((u32)f2bf(acc[7] * d) << 16);
                *(uint4*)&Asm[row][fbase] = o;
            }
        }
    } else {
        // 64-wide rows (layer 1): task = node, 32 tasks, 8/wave
        const int grp = lane >> 3;       // 0..7
        const int seg = lane & 7;        // 16-B feature segment
        for (int task = wave; task < 32; task += 4) {
            const int n = m0 + task;
            const int s = rowptr[n], e = rowptr[n + 1];
            float acc[8];
            if (grp == 0) {
                uint4 v = *(const uint4*)&U[(size_t)n * FIN + seg * 8];
                acc[0] = bf2f((u16)(v.x & 0xffff)); acc[1] = bf2f((u16)(v.x >> 16));
                acc[2] = bf2f((u16)(v.y & 0xffff)); acc[3] = bf2f((u16)(v.y >> 16));
                acc[4] = bf2f((u16)(v.z & 0xffff)); acc[5] = bf2f((u16)(v.z >> 16));
                acc[6] = bf2f((u16)(v.w & 0xffff)); acc[7] = bf2f((u16)(v.w >> 16));
            } else {
#pragma unroll
                for (int k = 0; k < 8; ++k) acc[k] = 0.f;
            }
            for (int j = s; j < e; j += 16) {
                int r0 = (int)ebuf[j + grp];
                int r1 = (int)ebuf[j + 8 + grp];
                uint4 v0 = *(const uint4*)&U[(size_t)r0 * FIN + seg * 8];
                uint4 v1 = *(const uint4*)&U[(size_t)r1 * FIN + seg * 8];
                acc[0] += bf2f((u16)(v0.x & 0xffff)); acc[1] += bf2f((u16)(v0.x >> 16));
                acc[2] += bf2f((u16)(v0.y & 0xffff)); acc[3] += bf2f((u16)(v0.y >> 16));
                acc[4] += bf2f((u16)(v0.z & 0xffff)); acc[5] += bf2f((u16)(v0.z >> 16));
                acc[6] += bf2f((u16)(v0.w & 0xffff)); acc[7] += bf2f((u16)(v0.w >> 16));
                acc[0] += bf2f((u16)(v1.x & 0xffff)); acc[1] += bf2f((u16)(v1.x >> 16));
                acc[2] += bf2f((u16)(v1.y & 0xffff)); acc[3] += bf2f((u16)(v1.y >> 16));
                acc[4] += bf2f((u16)(v1.z & 0xffff)); acc[5] += bf2f((u16)(v1.z >> 16));
                acc[6] += bf2f((u16)(v1.w & 0xffff)); acc[7] += bf2f((u16)(v1.w >> 16));
            }
#pragma unroll
            for (int off = 8; off < 64; off <<= 1)
#pragma unroll
                for (int k = 0; k < 8; ++k) acc[k] += __shfl_xor(acc[k], off);
            if (grp == 0) {
                float d = dinv[n];
                uint4 o;
                o.x = (u32)f2bf(acc[0] * d) | ((u32)f2bf(acc[1] * d) << 16);
                o.y = (u32)f2bf(acc[2] * d) | ((u32)f2bf(acc[3] * d) << 16);
                o.z = (u32)f2bf(acc[4] * d) | ((u32)f2bf(acc[5] * d) << 16);
                o.w = (u32)f2bf(acc[6] * d) | ((u32)f2bf(acc[7] * d) << 16);
                *(uint4*)&Asm[task][seg * 8] = o;
            }
        }
    }
    __syncthreads();

    // ---------------- MFMA phase ----------------
    const int quad = lane >> 4;
    const int l16 = lane & 15;
    const int n0 = wave * 64;
    f32x4 acc[2][4];
#pragma unroll
    for (int i = 0; i < 2; ++i)
#pragma unroll
        for (int j = 0; j < 4; ++j) acc[i][j] = (f32x4){0.f, 0.f, 0.f, 0.f};

    for (int k0 = 0; k0 < K; k0 += 32) {
#pragma unroll
        for (int j = 0; j < 4; ++j) {
            float4 v = *(const float4*)&Wt[(size_t)t * K + k0 + j * 8];
            *(float4*)&Bsm[t][j * 8] = v;
        }
        __syncthreads();
        short8 a[2], b[4];
#pragma unroll
        for (int i = 0; i < 2; ++i) a[i] = *(const short8*)&Asm[i * 16 + l16][k0 + quad * 8];
#pragma unroll
        for (int j = 0; j < 4; ++j) b[j] = *(const short8*)&Bsm[n0 + j * 16 + l16][quad * 8];
#pragma unroll
        for (int i = 0; i < 2; ++i)
#pragma unroll
            for (int j = 0; j < 4; ++j)
                acc[i][j] = __builtin_amdgcn_mfma_f32_16x16x32_bf16(a[i], b[j], acc[i][j], 0, 0, 0);
        __syncthreads();
    }
#pragma unroll
    for (int i = 0; i < 2; ++i) {
#pragma unroll
        for (int r = 0; r < 4; ++r) {
            int m = m0 + i * 16 + quad * 4 + r;
            float d = scaleOut ? dinv[m] : 1.0f;
#pragma unroll
            for (int j = 0; j < 4; ++j) {
                int n = n0 + j * 16 + l16;
                float val = fmaxf(acc[i][j][r] + bs[n], 0.f) * d;
                O[(size_t)m * HD + n] = f2bf(val);
            }
        }
    }
}

// ---------------- fused pool + head ----------------
__global__ __launch_bounds__(256) void k_poolout(const u16* __restrict__ h,
                                                 const int* __restrict__ gstart,
                                                 const float* __restrict__ Wout,
                                                 const float* __restrict__ bout,
                                                 float* __restrict__ out) {
    int g = blockIdx.x;
    int t = threadIdx.x;
    __shared__ float pooled[HD];
    __shared__ float part[NC][16];
    __shared__ int s_se[2];
    if (t == 0) {
        int st = gstart[g];
        int en = NN;
        for (int gg = g + 1; gg < NG; ++gg) en = min(en, gstart[gg]);
        s_se[0] = st; s_se[1] = en;
    }
    __syncthreads();
    int st = s_se[0], en = s_se[1];
    float a0 = 0.f, a1 = 0.f, a2 = 0.f, a3 = 0.f;
    int n = st;
    for (; n + 4 <= en; n += 4) {
        a0 += bf2f(h[(size_t)n * HD + t]);
        a1 += bf2f(h[(size_t)(n + 1) * HD + t]);
        a2 += bf2f(h[(size_t)(n + 2) * HD + t]);
        a3 += bf2f(h[(size_t)(n + 3) * HD + t]);
    }
    for (; n < en; ++n) a0 += bf2f(h[(size_t)n * HD + t]);
    float inv = 1.0f / (float)max(en - st, 1);
    pooled[t] = (a0 + a1 + a2 + a3) * inv;
    __syncthreads();
    if (t < NC * 16) {
        int c = t >> 4, l16 = t & 15;
        float s = 0.f;
        for (int f = l16; f < HD; f += 16)
            s = fmaf(pooled[f], Wout[(size_t)f * NC + c], s);
        part[c][l16] = s;
    }
    __syncthreads();
    if (t < NC) {
        float s = 0.f;
#pragma unroll
        for (int k = 0; k < 16; ++k) s += part[t][k];
        out[(size_t)g * NC + t] = s + bout[t];
    }
}

extern "C" void kernel_launch(void* const* d_in, const int* in_sizes, int n_in,
                              void* d_out, int out_size, void* d_ws, size_t ws_size,
                              hipStream_t stream) {
    const float* x     = (const float*)d_in[0];
    const int*   ei    = (const int*)d_in[1];
    const int*   batch = (const int*)d_in[2];
    const float* Wl[5] = {(const float*)d_in[3], (const float*)d_in[5], (const float*)d_in[7],
                          (const float*)d_in[9], (const float*)d_in[11]};
    const float* bl[5] = {(const float*)d_in[4], (const float*)d_in[6], (const float*)d_in[8],
                          (const float*)d_in[10], (const float*)d_in[12]};
    const float* Wout = (const float*)d_in[13];
    const float* bout = (const float*)d_in[14];
    float* out = (float*)d_out;

    const int* row = ei;
    const int* col = ei + NE;

    char* p = (char*)d_ws;
    auto take = [&](size_t bytes) { char* q = p; p += (bytes + 255) & ~(size_t)255; return q; };
    float* dinv   = (float*)take(NN * 4);
    int*   degi   = (int*)take(NN * 4);
    int*   rowptr = (int*)take((NN + 1) * 4);
    int*   cursor = (int*)take(NN * 4);
    int*   bsum   = (int*)take(NB * 4);
    u16*   ebuf   = (u16*)take(EBMAX * 2);
    int*   gstart = (int*)take(NG * 4);
    u16*   Wt[5];
    for (int l = 0; l < 5; ++l) Wt[l] = (u16*)take((size_t)HD * HD * 2);
    u16*   B1     = (u16*)take((size_t)(NN + 1) * HD * 2);   // +1 dummy zero row
    u16*   B2     = (u16*)take((size_t)(NN + 1) * HD * 2);

    hipMemsetAsync(degi, 0, NN * 4, stream);
    hipMemsetAsync(gstart, 0x7F, NG * 4, stream);   // sentinel > NN
    k_deg<<<(NE + 255) / 256, 256, 0, stream>>>(col, degi, batch, gstart);
    k_pad<<<(EBMAX / 2 + 255) / 256, 256, 0, stream>>>((u32*)ebuf);
    k_scan1<<<NB, 256, 0, stream>>>(degi, rowptr, bsum);
    k_scan3<<<(NN * FIN / 4 + 255) / 256, 256, 0, stream>>>(degi, bsum, rowptr, cursor, dinv, x, B1);
    k_fill<<<(NE + 255) / 256, 256, 0, stream>>>(row, col, cursor, ebuf);
    dim3 tGrid(8, 8, 5);
    k_trans<<<tGrid, 256, 0, stream>>>(Wl[0], Wl[1], Wl[2], Wl[3], Wl[4],
                                       Wt[0], Wt[1], Wt[2], Wt[3], Wt[4]);

    // 5 fused layers, ping-pong B1 <-> B2 (U != O, no read/write hazard)
    const int fGrid = NN / 32;   // 625, exact
    k_fused<<<fGrid, 256, 0, stream>>>(B1, rowptr, ebuf, dinv, Wt[0], bl[0], B2, FIN, 1);
    k_fused<<<fGrid, 256, 0, stream>>>(B2, rowptr, ebuf, dinv, Wt[1], bl[1], B1, HD, 1);
    k_fused<<<fGrid, 256, 0, stream>>>(B1, rowptr, ebuf, dinv, Wt[2], bl[2], B2, HD, 1);
    k_fused<<<fGrid, 256, 0, stream>>>(B2, rowptr, ebuf, dinv, Wt[3], bl[3], B1, HD, 1);
    k_fused<<<fGrid, 256, 0, stream>>>(B1, rowptr, ebuf, dinv, Wt[4], bl[4], B2, HD, 0);

    k_poolout<<<NG, 256, 0, stream>>>(B2, gstart, Wout, bout, out);
}

// Round 2
// 333.455 us; speedup vs baseline: 1.1867x; 1.1867x over previous
//
#include <hip/hip_runtime.h>

#define NN 20000
#define NE 320000
#define FIN 64
#define HD 256
#define NC 10
#define NG 64
#define NB ((NN + 255) / 256)      // 79 scan blocks
#define EBMAX (NE + 15 * NN + 16)  // padded CSR upper bound (u16 slots)

typedef unsigned short u16;
typedef unsigned int u32;
typedef __attribute__((ext_vector_type(8))) short short8;   // 8 bf16 (4 VGPRs)
typedef __attribute__((ext_vector_type(4))) float f32x4;    // 4 fp32 acc

__device__ __forceinline__ float bf2f(u16 u) {
    union { u32 i; float f; } v; v.i = ((u32)u) << 16; return v.f;
}
__device__ __forceinline__ u16 f2bf(float f) {
    union { float f; u32 i; } v; v.f = f;
    u32 r = v.i + 0x7fffu + ((v.i >> 16) & 1u);   // RNE
    return (u16)(r >> 16);
}

// ---------------- degree count + graph bounds (degi zeroed by memset) ------
__global__ void k_deg(const int* __restrict__ col, int* __restrict__ degi,
                      const int* __restrict__ batch, int* __restrict__ gstart) {
    int i = blockIdx.x * 256 + threadIdx.x;
    if (i < NE) atomicAdd(&degi[col[i]], 1);
    if (i < NN) {
        int b = batch[i];
        int prev = (i == 0) ? -1 : batch[i - 1];
        if (b != prev) gstart[b] = i;
    }
}

// ---------------- pad-fill ebuf with sentinel NN (0x4E20) ------------------
__global__ void k_pad(u32* __restrict__ ebuf32) {
    int i = blockIdx.x * 256 + threadIdx.x;
    if (i < EBMAX / 2) ebuf32[i] = 0x4E204E20u;   // two u16 = NN, NN
}

// ---------------- scan stage 1: padded-degree block scan + block sums ------
__global__ __launch_bounds__(256) void k_scan1(const int* __restrict__ degi,
                                               int* __restrict__ rowptr,
                                               int* __restrict__ bsum) {
    int t = threadIdx.x;
    int i = blockIdx.x * 256 + t;
    int v = (i < NN) ? ((degi[i] + 15) & ~15) : 0;   // padded degree
    int lane = t & 63, wid = t >> 6;
    int x = v;
#pragma unroll
    for (int off = 1; off < 64; off <<= 1) {
        int y = __shfl_up(x, off);
        if (lane >= off) x += y;
    }
    __shared__ int ws[4];
    if (lane == 63) ws[wid] = x;
    __syncthreads();
    int woff = 0;
    for (int w = 0; w < wid; ++w) woff += ws[w];
    if (i < NN) rowptr[i] = woff + x - v;
    if (t == 255) bsum[blockIdx.x] = woff + x;
}

// ---------------- scan 2+3 fused: fixup + cursor + dinv + u0 (+zero row NN)
__global__ void k_scan3(const int* __restrict__ degi, const int* __restrict__ bsum,
                        int* __restrict__ rowptr, int* __restrict__ cursor,
                        float* __restrict__ dinv,
                        const float* __restrict__ x, u16* __restrict__ u0) {
    __shared__ int pref[NB];
    if (threadIdx.x < NB) pref[threadIdx.x] = bsum[threadIdx.x];
    __syncthreads();
    if (threadIdx.x == 0) {
        int run = 0;
        for (int k = 0; k < NB; ++k) { int t = pref[k]; pref[k] = run; run += t; }
    }
    __syncthreads();
    int i = blockIdx.x * 256 + threadIdx.x;
    if (i < NN) {
        int dg = degi[i];
        int rp = rowptr[i] + pref[i >> 8];
        rowptr[i] = rp;
        cursor[i] = rp;
        dinv[i] = rsqrtf((float)(1 + dg));
        if (i == NN - 1) rowptr[NN] = rp + ((dg + 15) & ~15);
    }
    if (i < NN * FIN / 4) {
        int node = i >> 4;
        float d = rsqrtf((float)(1 + degi[node]));
        float4 v = *(const float4*)&x[(size_t)i * 4];
        u32 lo = (u32)f2bf(v.x * d) | ((u32)f2bf(v.y * d) << 16);
        u32 hi = (u32)f2bf(v.z * d) | ((u32)f2bf(v.w * d) << 16);
        *(uint2*)&u0[(size_t)i * 4] = make_uint2(lo, hi);
    }
    if (blockIdx.x == 0 && threadIdx.x < FIN) u0[(size_t)NN * FIN + threadIdx.x] = 0;  // dummy row
}

// ---------------- fill CSR buckets (u16 payload) ----------------
__global__ void k_fill(const int* __restrict__ row, const int* __restrict__ col,
                       int* __restrict__ cursor, u16* __restrict__ ebuf) {
    int e = blockIdx.x * 256 + threadIdx.x;
    if (e < NE) {
        int c = col[e];
        int pos = atomicAdd(&cursor[c], 1);
        ebuf[pos] = (u16)row[e];
    }
}

// ---------------- LDS-tiled transpose+cast of all 5 W ----------------
__global__ __launch_bounds__(256) void k_trans(const float* __restrict__ W0, const float* __restrict__ W1,
                                               const float* __restrict__ W2, const float* __restrict__ W3,
                                               const float* __restrict__ W4,
                                               u16* __restrict__ T0, u16* __restrict__ T1,
                                               u16* __restrict__ T2, u16* __restrict__ T3,
                                               u16* __restrict__ T4) {
    int l = blockIdx.z;
    const float* W = (l == 0) ? W0 : (l == 1) ? W1 : (l == 2) ? W2 : (l == 3) ? W3 : W4;
    u16* T = (l == 0) ? T0 : (l == 1) ? T1 : (l == 2) ? T2 : (l == 3) ? T3 : T4;
    int K = (l == 0) ? FIN : HD;
    int k0 = blockIdx.x * 32;
    if (k0 >= K) return;
    int n0 = blockIdx.y * 32;
    __shared__ float tile[32][33];
    int tx = threadIdx.x & 31, ty = threadIdx.x >> 5;
#pragma unroll
    for (int r = 0; r < 32; r += 8)
        tile[ty + r][tx] = W[(size_t)(k0 + ty + r) * HD + n0 + tx];
    __syncthreads();
#pragma unroll
    for (int r = 0; r < 32; r += 8)
        T[(size_t)(n0 + ty + r) * K + k0 + tx] = f2bf(tile[tx][ty + r]);
}

// ============ FUSED gather(aggregate) + MFMA matmul, 16-row tile/block =====
// 1250 blocks x 512 threads (8 waves): 4x the waves of the 32-row version,
// 32 waves/CU nominal occupancy (LDS 30 KB -> 4 blocks/CU).
// Gather: 32 tasks (16 nodes x 2 halves) -> 4 serial tasks/wave (K=256).
// MFMA: each wave owns M16 x N32 (acc[1][2], 8 VGPR) -> fits 64-VGPR budget.
__global__ __launch_bounds__(512, 8) void k_fused(const u16* __restrict__ U,
                                                  const int* __restrict__ rowptr,
                                                  const u16* __restrict__ ebuf,
                                                  const float* __restrict__ dinv,
                                                  const u16* __restrict__ Wt,
                                                  const float* __restrict__ bias,
                                                  u16* __restrict__ O,
                                                  int K, int scaleOut) {
    __shared__ u16 Asm[16][264];     // 16 rows x (K<=256 + 8 pad) bf16
    __shared__ u16 Bsm[256][40];
    __shared__ float bs[HD];
    const int m0 = blockIdx.x * 16;  // 1250 * 16 == 20000, exact
    const int t = threadIdx.x;
    const int wave = t >> 6;         // 0..7
    const int lane = t & 63;
    if (t < HD) bs[t] = bias[t];
    if (blockIdx.x == 0 && t < HD) O[(size_t)NN * HD + t] = 0;   // dummy row

    // ---------------- gather phase ----------------
    if (K == HD) {
        // 256-wide rows: task = (row, half), 32 tasks, 4/wave
        const int grp = lane >> 4;       // 0..3
        const int seg = lane & 15;       // 16-B segment within half
        for (int task = wave; task < 32; task += 8) {
            const int row = task >> 1;
            const int n = m0 + row;
            const int fbase = (task & 1) * 128 + seg * 8;
            const int s = rowptr[n], e = rowptr[n + 1];
            float acc[8];
            if (grp == 0) {              // self-loop
                uint4 v = *(const uint4*)&U[(size_t)n * HD + fbase];
                acc[0] = bf2f((u16)(v.x & 0xffff)); acc[1] = bf2f((u16)(v.x >> 16));
                acc[2] = bf2f((u16)(v.y & 0xffff)); acc[3] = bf2f((u16)(v.y >> 16));
                acc[4] = bf2f((u16)(v.z & 0xffff)); acc[5] = bf2f((u16)(v.z >> 16));
                acc[6] = bf2f((u16)(v.w & 0xffff)); acc[7] = bf2f((u16)(v.w >> 16));
            } else {
#pragma unroll
                for (int k = 0; k < 8; ++k) acc[k] = 0.f;
            }
            for (int j = s; j < e; j += 16) {
                int myid = (lane < 16) ? (int)ebuf[j + lane] : 0;  // pads -> row NN
                uint4 v[4];
#pragma unroll
                for (int k = 0; k < 4; ++k) {
                    int r = __shfl(myid, grp * 4 + k);
                    v[k] = *(const uint4*)&U[(size_t)r * HD + fbase];
                }
#pragma unroll
                for (int k = 0; k < 4; ++k) {
                    acc[0] += bf2f((u16)(v[k].x & 0xffff)); acc[1] += bf2f((u16)(v[k].x >> 16));
                    acc[2] += bf2f((u16)(v[k].y & 0xffff)); acc[3] += bf2f((u16)(v[k].y >> 16));
                    acc[4] += bf2f((u16)(v[k].z & 0xffff)); acc[5] += bf2f((u16)(v[k].z >> 16));
                    acc[6] += bf2f((u16)(v[k].w & 0xffff)); acc[7] += bf2f((u16)(v[k].w >> 16));
                }
            }
#pragma unroll
            for (int k = 0; k < 8; ++k) {
                acc[k] += __shfl_xor(acc[k], 16);
                acc[k] += __shfl_xor(acc[k], 32);
            }
            if (grp == 0) {
                float d = dinv[n];
                uint4 o;
                o.x = (u32)f2bf(acc[0] * d) | ((u32)f2bf(acc[1] * d) << 16);
                o.y = (u32)f2bf(acc[2] * d) | ((u32)f2bf(acc[3] * d) << 16);
                o.z = (u32)f2bf(acc[4] * d) | ((u32)f2bf(acc[5] * d) << 16);
                o.w = (u32)f2bf(acc[6] * d) | ((u32)f2bf(acc[7] * d) << 16);
                *(uint4*)&Asm[row][fbase] = o;
            }
        }
    } else {
        // 64-wide rows (layer 1): task = node, 16 tasks, 2/wave
        const int grp = lane >> 3;       // 0..7
        const int seg = lane & 7;        // 16-B feature segment
        for (int task = wave; task < 16; task += 8) {
            const int n = m0 + task;
            const int s = rowptr[n], e = rowptr[n + 1];
            float acc[8];
            if (grp == 0) {
                uint4 v = *(const uint4*)&U[(size_t)n * FIN + seg * 8];
                acc[0] = bf2f((u16)(v.x & 0xffff)); acc[1] = bf2f((u16)(v.x >> 16));
                acc[2] = bf2f((u16)(v.y & 0xffff)); acc[3] = bf2f((u16)(v.y >> 16));
                acc[4] = bf2f((u16)(v.z & 0xffff)); acc[5] = bf2f((u16)(v.z >> 16));
                acc[6] = bf2f((u16)(v.w & 0xffff)); acc[7] = bf2f((u16)(v.w >> 16));
            } else {
#pragma unroll
                for (int k = 0; k < 8; ++k) acc[k] = 0.f;
            }
            for (int j = s; j < e; j += 16) {
                int r0 = (int)ebuf[j + grp];
                int r1 = (int)ebuf[j + 8 + grp];
                uint4 v0 = *(const uint4*)&U[(size_t)r0 * FIN + seg * 8];
                uint4 v1 = *(const uint4*)&U[(size_t)r1 * FIN + seg * 8];
                acc[0] += bf2f((u16)(v0.x & 0xffff)); acc[1] += bf2f((u16)(v0.x >> 16));
                acc[2] += bf2f((u16)(v0.y & 0xffff)); acc[3] += bf2f((u16)(v0.y >> 16));
                acc[4] += bf2f((u16)(v0.z & 0xffff)); acc[5] += bf2f((u16)(v0.z >> 16));
                acc[6] += bf2f((u16)(v0.w & 0xffff)); acc[7] += bf2f((u16)(v0.w >> 16));
                acc[0] += bf2f((u16)(v1.x & 0xffff)); acc[1] += bf2f((u16)(v1.x >> 16));
                acc[2] += bf2f((u16)(v1.y & 0xffff)); acc[3] += bf2f((u16)(v1.y >> 16));
                acc[4] += bf2f((u16)(v1.z & 0xffff)); acc[5] += bf2f((u16)(v1.z >> 16));
                acc[6] += bf2f((u16)(v1.w & 0xffff)); acc[7] += bf2f((u16)(v1.w >> 16));
            }
#pragma unroll
            for (int off = 8; off < 64; off <<= 1)
#pragma unroll
                for (int k = 0; k < 8; ++k) acc[k] += __shfl_xor(acc[k], off);
            if (grp == 0) {
                float d = dinv[n];
                uint4 o;
                o.x = (u32)f2bf(acc[0] * d) | ((u32)f2bf(acc[1] * d) << 16);
                o.y = (u32)f2bf(acc[2] * d) | ((u32)f2bf(acc[3] * d) << 16);
                o.z = (u32)f2bf(acc[4] * d) | ((u32)f2bf(acc[5] * d) << 16);
                o.w = (u32)f2bf(acc[6] * d) | ((u32)f2bf(acc[7] * d) << 16);
                *(uint4*)&Asm[task][seg * 8] = o;
            }
        }
    }
    __syncthreads();

    // ---------------- MFMA phase ----------------
    const int quad = lane >> 4;
    const int l16 = lane & 15;
    const int n0 = wave * 32;        // wave owns N columns [n0, n0+32)
    f32x4 acc[2];
#pragma unroll
    for (int j = 0; j < 2; ++j) acc[j] = (f32x4){0.f, 0.f, 0.f, 0.f};

    for (int k0 = 0; k0 < K; k0 += 32) {
        {   // stage Wt[:, k0:k0+32] (16 KB) with all 512 threads
            int r = t >> 1, h16 = (t & 1) * 16;
#pragma unroll
            for (int j = 0; j < 2; ++j) {
                float4 v = *(const float4*)&Wt[(size_t)r * K + k0 + h16 + j * 8];
                *(float4*)&Bsm[r][h16 + j * 8] = v;
            }
        }
        __syncthreads();
        short8 a = *(const short8*)&Asm[l16][k0 + quad * 8];
        short8 b[2];
#pragma unroll
        for (int j = 0; j < 2; ++j) b[j] = *(const short8*)&Bsm[n0 + j * 16 + l16][quad * 8];
#pragma unroll
        for (int j = 0; j < 2; ++j)
            acc[j] = __builtin_amdgcn_mfma_f32_16x16x32_bf16(a, b[j], acc[j], 0, 0, 0);
        __syncthreads();
    }
#pragma unroll
    for (int r = 0; r < 4; ++r) {
        int m = m0 + quad * 4 + r;
        float d = scaleOut ? dinv[m] : 1.0f;
#pragma unroll
        for (int j = 0; j < 2; ++j) {
            int n = n0 + j * 16 + l16;
            float val = fmaxf(acc[j][r] + bs[n], 0.f) * d;
            O[(size_t)m * HD + n] = f2bf(val);
        }
    }
}

// ---------------- fused pool + head ----------------
__global__ __launch_bounds__(256) void k_poolout(const u16* __restrict__ h,
                                                 const int* __restrict__ gstart,
                                                 const float* __restrict__ Wout,
                                                 const float* __restrict__ bout,
                                                 float* __restrict__ out) {
    int g = blockIdx.x;
    int t = threadIdx.x;
    __shared__ float pooled[HD];
    __shared__ float part[NC][16];
    __shared__ int s_se[2];
    if (t == 0) {
        int st = gstart[g];
        int en = NN;
        for (int gg = g + 1; gg < NG; ++gg) en = min(en, gstart[gg]);
        s_se[0] = st; s_se[1] = en;
    }
    __syncthreads();
    int st = s_se[0], en = s_se[1];
    float a0 = 0.f, a1 = 0.f, a2 = 0.f, a3 = 0.f;
    int n = st;
    for (; n + 4 <= en; n += 4) {
        a0 += bf2f(h[(size_t)n * HD + t]);
        a1 += bf2f(h[(size_t)(n + 1) * HD + t]);
        a2 += bf2f(h[(size_t)(n + 2) * HD + t]);
        a3 += bf2f(h[(size_t)(n + 3) * HD + t]);
    }
    for (; n < en; ++n) a0 += bf2f(h[(size_t)n * HD + t]);
    float inv = 1.0f / (float)max(en - st, 1);
    pooled[t] = (a0 + a1 + a2 + a3) * inv;
    __syncthreads();
    if (t < NC * 16) {
        int c = t >> 4, l16 = t & 15;
        float s = 0.f;
        for (int f = l16; f < HD; f += 16)
            s = fmaf(pooled[f], Wout[(size_t)f * NC + c], s);
        part[c][l16] = s;
    }
    __syncthreads();
    if (t < NC) {
        float s = 0.f;
#pragma unroll
        for (int k = 0; k < 16; ++k) s += part[t][k];
        out[(size_t)g * NC + t] = s + bout[t];
    }
}

extern "C" void kernel_launch(void* const* d_in, const int* in_sizes, int n_in,
                              void* d_out, int out_size, void* d_ws, size_t ws_size,
                              hipStream_t stream) {
    const float* x     = (const float*)d_in[0];
    const int*   ei    = (const int*)d_in[1];
    const int*   batch = (const int*)d_in[2];
    const float* Wl[5] = {(const float*)d_in[3], (const float*)d_in[5], (const float*)d_in[7],
                          (const float*)d_in[9], (const float*)d_in[11]};
    const float* bl[5] = {(const float*)d_in[4], (const float*)d_in[6], (const float*)d_in[8],
                          (const float*)d_in[10], (const float*)d_in[12]};
    const float* Wout = (const float*)d_in[13];
    const float* bout = (const float*)d_in[14];
    float* out = (float*)d_out;

    const int* row = ei;
    const int* col = ei + NE;

    char* p = (char*)d_ws;
    auto take = [&](size_t bytes) { char* q = p; p += (bytes + 255) & ~(size_t)255; return q; };
    float* dinv   = (float*)take(NN * 4);
    int*   degi   = (int*)take(NN * 4);
    int*   rowptr = (int*)take((NN + 1) * 4);
    int*   cursor = (int*)take(NN * 4);
    int*   bsum   = (int*)take(NB * 4);
    u16*   ebuf   = (u16*)take(EBMAX * 2);
    int*   gstart = (int*)take(NG * 4);
    u16*   Wt[5];
    for (int l = 0; l < 5; ++l) Wt[l] = (u16*)take((size_t)HD * HD * 2);
    u16*   B1     = (u16*)take((size_t)(NN + 1) * HD * 2);   // +1 dummy zero row
    u16*   B2     = (u16*)take((size_t)(NN + 1) * HD * 2);

    hipMemsetAsync(degi, 0, NN * 4, stream);
    hipMemsetAsync(gstart, 0x7F, NG * 4, stream);   // sentinel > NN
    k_deg<<<(NE + 255) / 256, 256, 0, stream>>>(col, degi, batch, gstart);
    k_pad<<<(EBMAX / 2 + 255) / 256, 256, 0, stream>>>((u32*)ebuf);
    k_scan1<<<NB, 256, 0, stream>>>(degi, rowptr, bsum);
    k_scan3<<<(NN * FIN / 4 + 255) / 256, 256, 0, stream>>>(degi, bsum, rowptr, cursor, dinv, x, B1);
    k_fill<<<(NE + 255) / 256, 256, 0, stream>>>(row, col, cursor, ebuf);
    dim3 tGrid(8, 8, 5);
    k_trans<<<tGrid, 256, 0, stream>>>(Wl[0], Wl[1], Wl[2], Wl[3], Wl[4],
                                       Wt[0], Wt[1], Wt[2], Wt[3], Wt[4]);

    // 5 fused layers, ping-pong B1 <-> B2 (U != O, no read/write hazard)
    const int fGrid = NN / 16;   // 1250, exact
    k_fused<<<fGrid, 512, 0, stream>>>(B1, rowptr, ebuf, dinv, Wt[0], bl[0], B2, FIN, 1);
    k_fused<<<fGrid, 512, 0, stream>>>(B2, rowptr, ebuf, dinv, Wt[1], bl[1], B1, HD, 1);
    k_fused<<<fGrid, 512, 0, stream>>>(B1, rowptr, ebuf, dinv, Wt[2], bl[2], B2, HD, 1);
    k_fused<<<fGrid, 512, 0, stream>>>(B2, rowptr, ebuf, dinv, Wt[3], bl[3], B1, HD, 1);
    k_fused<<<fGrid, 512, 0, stream>>>(B1, rowptr, ebuf, dinv, Wt[4], bl[4], B2, HD, 0);

    k_poolout<<<NG, 256, 0, stream>>>(B2, gstart, Wout, bout, out);
}